// Round 8
// baseline (85.596 us; speedup 1.0000x reference)
//
#include <hip/hip_runtime.h>

#define T_TOKENS 8192
#define MAX_NODES 8192
#define FEAT 256
#define NCHUNKS 1024
#define CHUNK 8                  // T_TOKENS / NCHUNKS
#define NSUPER 32
#define SUPER 32                 // chunks per supergroup
#define LIST_CAP 4096            // events/chunk cap (expected ~8, huge margin)

#define APPLY_EVENT(eV, vV)                          \
    {                                                \
        const float sv_ = ((eV) & 1) ? -(vV) : (vV); \
        const int lr_ = ((eV) >> 1) & 7;             \
        d0 += (lr_ == 0) ? sv_ : 0.f;                \
        d1 += (lr_ == 1) ? sv_ : 0.f;                \
        d2 += (lr_ == 2) ? sv_ : 0.f;                \
        d3 += (lr_ == 3) ? sv_ : 0.f;                \
        d4 += (lr_ == 4) ? sv_ : 0.f;                \
        d5 += (lr_ == 5) ? sv_ : 0.f;                \
        d6 += (lr_ == 6) ? sv_ : 0.f;                \
        d7 += (lr_ == 7) ? sv_ : 0.f;                \
    }

// K1: block c classifies ALL nodes in one pass (each thread scans 32 nodes
// via int4 loads), applies its chunk's ~8 events into 8 register rows, then
// stores the materialized diff tile (coalesced), colsum = row total, and
// atomically folds colsum into supersum (zeroed by a memset node).
// entry = (node << 4) | (local_row << 1) | sign, local_row in [0,8)
__global__ __launch_bounds__(FEAT) void classify_diff_kernel(
    const float* __restrict__ emb,
    const int* __restrict__ starts,
    const int* __restrict__ ends,
    const int* __restrict__ num_nodes_p,
    float* __restrict__ diff,
    float* __restrict__ colsum,
    float* __restrict__ supersum) {
    __shared__ int s_list[LIST_CAP];   // 16 KB
    __shared__ int s_cnt;
    const int c = blockIdx.x;
    const int tid = threadIdx.x;
    const int f = tid;
    const int num_nodes = *num_nodes_p;
    const int row_lo = c * CHUNK;
    const int row_hi = row_lo + CHUNK;
    const int4* starts4 = (const int4*)starts;
    const int4* ends4 = (const int4*)ends;

    if (tid == 0) s_cnt = 0;
    __syncthreads();
#pragma unroll
    for (int r = 0; r < MAX_NODES / (4 * FEAT); ++r) {   // 8 rounds x 1024 nodes
        const int vec = r * FEAT + tid;
        const int4 s4 = starts4[vec];
        const int4 e4 = ends4[vec];
        const int sv[4] = {s4.x, s4.y, s4.z, s4.w};
        const int ev[4] = {e4.x, e4.y, e4.z, e4.w};
        const int nb = vec * 4;
#pragma unroll
        for (int k = 0; k < 4; ++k) {
            const int node = nb + k;
            const int s = sv[k];
            const int e = ev[k];
            if (node < num_nodes && s <= e && s < T_TOKENS && e >= 0) {
                const int sc = s < 0 ? 0 : s;
                if (sc >= row_lo && sc < row_hi) {
                    int p = atomicAdd(&s_cnt, 1);
                    if (p < LIST_CAP) s_list[p] = (node << 4) | ((sc - row_lo) << 1);
                }
                const int e1 = e + 1;
                if (e1 < T_TOKENS && e1 >= row_lo && e1 < row_hi) {
                    int p = atomicAdd(&s_cnt, 1);
                    if (p < LIST_CAP) s_list[p] = (node << 4) | ((e1 - row_lo) << 1) | 1;
                }
            }
        }
    }
    __syncthreads();
    const int cnt = min(s_cnt, LIST_CAP);

    // apply events into 8 register rows, 4 emb rows in flight
    float d0 = 0.f, d1 = 0.f, d2 = 0.f, d3 = 0.f;
    float d4 = 0.f, d5 = 0.f, d6 = 0.f, d7 = 0.f;
    int j = 0;
    for (; j + 4 <= cnt; j += 4) {
        const int e0 = s_list[j + 0], e1 = s_list[j + 1];
        const int e2 = s_list[j + 2], e3 = s_list[j + 3];
        const float v0 = emb[(size_t)(e0 >> 4) * FEAT + f];
        const float v1 = emb[(size_t)(e1 >> 4) * FEAT + f];
        const float v2 = emb[(size_t)(e2 >> 4) * FEAT + f];
        const float v3 = emb[(size_t)(e3 >> 4) * FEAT + f];
        APPLY_EVENT(e0, v0);
        APPLY_EVENT(e1, v1);
        APPLY_EVENT(e2, v2);
        APPLY_EVENT(e3, v3);
    }
    for (; j < cnt; ++j) {
        const int e0 = s_list[j];
        const float v0 = emb[(size_t)(e0 >> 4) * FEAT + f];
        APPLY_EVENT(e0, v0);
    }

    // materialize the diff tile (coalesced stores) + colsum + supersum
    float* dt = diff + (size_t)c * CHUNK * FEAT + f;
    dt[0 * FEAT] = d0; dt[1 * FEAT] = d1;
    dt[2 * FEAT] = d2; dt[3 * FEAT] = d3;
    dt[4 * FEAT] = d4; dt[5 * FEAT] = d5;
    dt[6 * FEAT] = d6; dt[7 * FEAT] = d7;
    const float acc = ((d0 + d1) + (d2 + d3)) + ((d4 + d5) + (d6 + d7));
    colsum[(size_t)c * FEAT + f] = acc;
    atomicAdd(&supersum[(size_t)(c >> 5) * FEAT + f], acc);
}

// K3: pure streaming. Hoist the 8 independent diff-row loads so they're in
// flight during the two-level prefix (<=31 supersum + <=31 colsum rows,
// 8 in flight), then register scan + coalesced stores. No scattered access.
__global__ __launch_bounds__(FEAT) void scan_kernel(
    const float* __restrict__ diff,
    const float* __restrict__ colsum,
    const float* __restrict__ supersum,
    float* __restrict__ out) {
    const int c = blockIdx.x;
    const int f = threadIdx.x;
    const int sg = c >> 5;

    // issue diff-tile loads first (independent of the prefix chain)
    const float* dt = diff + (size_t)c * CHUNK * FEAT + f;
    const float d0 = dt[0 * FEAT], d1 = dt[1 * FEAT];
    const float d2 = dt[2 * FEAT], d3 = dt[3 * FEAT];
    const float d4 = dt[4 * FEAT], d5 = dt[5 * FEAT];
    const float d6 = dt[6 * FEAT], d7 = dt[7 * FEAT];

    float r0 = 0.f, r1 = 0.f, r2 = 0.f, r3 = 0.f;
    float r4 = 0.f, r5 = 0.f, r6 = 0.f, r7 = 0.f;
    int i = 0;
    for (; i + 8 <= sg; i += 8) {
        r0 += supersum[(size_t)(i + 0) * FEAT + f];
        r1 += supersum[(size_t)(i + 1) * FEAT + f];
        r2 += supersum[(size_t)(i + 2) * FEAT + f];
        r3 += supersum[(size_t)(i + 3) * FEAT + f];
        r4 += supersum[(size_t)(i + 4) * FEAT + f];
        r5 += supersum[(size_t)(i + 5) * FEAT + f];
        r6 += supersum[(size_t)(i + 6) * FEAT + f];
        r7 += supersum[(size_t)(i + 7) * FEAT + f];
    }
    for (; i < sg; ++i) r0 += supersum[(size_t)i * FEAT + f];
    i = sg * SUPER;
    for (; i + 8 <= c; i += 8) {
        r0 += colsum[(size_t)(i + 0) * FEAT + f];
        r1 += colsum[(size_t)(i + 1) * FEAT + f];
        r2 += colsum[(size_t)(i + 2) * FEAT + f];
        r3 += colsum[(size_t)(i + 3) * FEAT + f];
        r4 += colsum[(size_t)(i + 4) * FEAT + f];
        r5 += colsum[(size_t)(i + 5) * FEAT + f];
        r6 += colsum[(size_t)(i + 6) * FEAT + f];
        r7 += colsum[(size_t)(i + 7) * FEAT + f];
    }
    for (; i < c; ++i) r0 += colsum[(size_t)i * FEAT + f];
    float run = ((r0 + r1) + (r2 + r3)) + ((r4 + r5) + (r6 + r7));

    float* o = out + (size_t)c * CHUNK * FEAT + f;
    run += d0; o[0 * FEAT] = run;
    run += d1; o[1 * FEAT] = run;
    run += d2; o[2 * FEAT] = run;
    run += d3; o[3 * FEAT] = run;
    run += d4; o[4 * FEAT] = run;
    run += d5; o[5 * FEAT] = run;
    run += d6; o[6 * FEAT] = run;
    run += d7; o[7 * FEAT] = run;
}

extern "C" void kernel_launch(void* const* d_in, const int* in_sizes, int n_in,
                              void* d_out, int out_size, void* d_ws, size_t ws_size,
                              hipStream_t stream) {
    const float* emb     = (const float*)d_in[0];
    const int* starts    = (const int*)d_in[1];
    const int* ends      = (const int*)d_in[2];
    const int* num_nodes = (const int*)d_in[3];
    float* out           = (float*)d_out;

    float* colsum   = (float*)d_ws;                              // 1 MB
    float* supersum = colsum + (size_t)NCHUNKS * FEAT;           // 32 KB
    float* diff     = supersum + (size_t)NSUPER * FEAT;          // 8 MB

    // supersum accumulated via atomics -> must start at zero
    hipMemsetAsync(supersum, 0, (size_t)NSUPER * FEAT * sizeof(float), stream);

    classify_diff_kernel<<<NCHUNKS, FEAT, 0, stream>>>(
        emb, starts, ends, num_nodes, diff, colsum, supersum);
    scan_kernel<<<NCHUNKS, FEAT, 0, stream>>>(diff, colsum, supersum, out);
}

// Round 9
// 83.141 us; speedup vs baseline: 1.0295x; 1.0295x over previous
//
#include <hip/hip_runtime.h>

#define T_TOKENS 8192
#define MAX_NODES 8192
#define FEAT 256
#define NCHUNKS 1024
#define CHUNK 8                  // T_TOKENS / NCHUNKS
#define NSUPER 32
#define SUPER 32                 // chunks per supergroup
#define LIST_CAP 4096            // events/chunk cap (expected ~18, huge margin)
#define EV_STRIDE LIST_CAP

// K1: block c (1024 blocks, 4/CU) classifies ALL nodes in ONE pass (each
// thread scans 32 nodes via int4 loads), flushes its chunk's events to
// evbuf[c], computes colsum[c][f] with 8 emb-row loads in flight, and
// atomically folds colsum into supersum[c/32][f] (zeroed by memset node).
// entry = (node << 4) | (local_row << 1) | sign, local_row in [0,8)
__global__ __launch_bounds__(FEAT) void classify_colsum_kernel(
    const float* __restrict__ emb,
    const int* __restrict__ starts,
    const int* __restrict__ ends,
    const int* __restrict__ num_nodes_p,
    float* __restrict__ colsum,
    float* __restrict__ supersum,
    int* __restrict__ evcnt,
    int* __restrict__ evbuf) {
    __shared__ int s_list[LIST_CAP];   // 16 KB
    __shared__ int s_cnt;
    const int c = blockIdx.x;
    const int tid = threadIdx.x;
    const int f = tid;
    const int num_nodes = *num_nodes_p;
    const int row_lo = c * CHUNK;
    const int row_hi = row_lo + CHUNK;
    const int4* starts4 = (const int4*)starts;
    const int4* ends4 = (const int4*)ends;

    if (tid == 0) s_cnt = 0;
    __syncthreads();
#pragma unroll
    for (int r = 0; r < MAX_NODES / (4 * FEAT); ++r) {   // 8 rounds x 1024 nodes
        const int vec = r * FEAT + tid;
        const int4 s4 = starts4[vec];
        const int4 e4 = ends4[vec];
        const int sv[4] = {s4.x, s4.y, s4.z, s4.w};
        const int ev[4] = {e4.x, e4.y, e4.z, e4.w};
        const int nb = vec * 4;
#pragma unroll
        for (int k = 0; k < 4; ++k) {
            const int node = nb + k;
            const int s = sv[k];
            const int e = ev[k];
            if (node < num_nodes && s <= e && s < T_TOKENS && e >= 0) {
                const int sc = s < 0 ? 0 : s;
                if (sc >= row_lo && sc < row_hi) {
                    int p = atomicAdd(&s_cnt, 1);
                    if (p < LIST_CAP) s_list[p] = (node << 4) | ((sc - row_lo) << 1);
                }
                const int e1 = e + 1;
                if (e1 < T_TOKENS && e1 >= row_lo && e1 < row_hi) {
                    int p = atomicAdd(&s_cnt, 1);
                    if (p < LIST_CAP) s_list[p] = (node << 4) | ((e1 - row_lo) << 1) | 1;
                }
            }
        }
    }
    __syncthreads();
    const int cnt = min(s_cnt, LIST_CAP);

    // flush events to global (coalesced; ~18 ints typical)
    int* evb = evbuf + (size_t)c * EV_STRIDE;
    for (int j = tid; j < cnt; j += FEAT) evb[j] = s_list[j];
    if (tid == 0) evcnt[c] = cnt;

    // gather signed emb rows, 8 loads in flight
    float acc = 0.f;
    int j = 0;
    for (; j + 8 <= cnt; j += 8) {
        const int e0 = s_list[j + 0], e1 = s_list[j + 1];
        const int e2 = s_list[j + 2], e3 = s_list[j + 3];
        const int e4_ = s_list[j + 4], e5 = s_list[j + 5];
        const int e6 = s_list[j + 6], e7 = s_list[j + 7];
        const float v0 = emb[(size_t)(e0 >> 4) * FEAT + f];
        const float v1 = emb[(size_t)(e1 >> 4) * FEAT + f];
        const float v2 = emb[(size_t)(e2 >> 4) * FEAT + f];
        const float v3 = emb[(size_t)(e3 >> 4) * FEAT + f];
        const float v4 = emb[(size_t)(e4_ >> 4) * FEAT + f];
        const float v5 = emb[(size_t)(e5 >> 4) * FEAT + f];
        const float v6 = emb[(size_t)(e6 >> 4) * FEAT + f];
        const float v7 = emb[(size_t)(e7 >> 4) * FEAT + f];
        acc += (e0 & 1) ? -v0 : v0;
        acc += (e1 & 1) ? -v1 : v1;
        acc += (e2 & 1) ? -v2 : v2;
        acc += (e3 & 1) ? -v3 : v3;
        acc += (e4_ & 1) ? -v4 : v4;
        acc += (e5 & 1) ? -v5 : v5;
        acc += (e6 & 1) ? -v6 : v6;
        acc += (e7 & 1) ? -v7 : v7;
    }
    for (; j < cnt; ++j) {
        const int e0 = s_list[j];
        const float v0 = emb[(size_t)(e0 >> 4) * FEAT + f];
        acc += (e0 & 1) ? -v0 : v0;
    }
    colsum[(size_t)c * FEAT + f] = acc;
    atomicAdd(&supersum[(size_t)(c >> 5) * FEAT + f], acc);
}

#define APPLY_EVENT(eV, vV)                          \
    {                                                \
        const float sv_ = ((eV) & 1) ? -(vV) : (vV); \
        const int lr_ = ((eV) >> 1) & 7;             \
        d0 += (lr_ == 0) ? sv_ : 0.f;                \
        d1 += (lr_ == 1) ? sv_ : 0.f;                \
        d2 += (lr_ == 2) ? sv_ : 0.f;                \
        d3 += (lr_ == 3) ? sv_ : 0.f;                \
        d4 += (lr_ == 4) ? sv_ : 0.f;                \
        d5 += (lr_ == 5) ? sv_ : 0.f;                \
        d6 += (lr_ == 6) ? sv_ : 0.f;                \
        d7 += (lr_ == 7) ? sv_ : 0.f;                \
    }

// K3: block c: 2-level exclusive prefix (<=31 supersum + <=31 colsum rows,
// 8 in flight), replay event list from evbuf into 8 register rows
// (no LDS, no barriers), scan + coalesced store.
__global__ __launch_bounds__(FEAT) void scan_kernel(
    const float* __restrict__ emb,
    const float* __restrict__ colsum,
    const float* __restrict__ supersum,
    const int* __restrict__ evcnt,
    const int* __restrict__ evbuf,
    float* __restrict__ out) {
    const int c = blockIdx.x;
    const int f = threadIdx.x;
    const int sg = c >> 5;

    const int cnt = evcnt[c];
    const int* evb = evbuf + (size_t)c * EV_STRIDE;

    float r0 = 0.f, r1 = 0.f, r2 = 0.f, r3 = 0.f;
    float r4 = 0.f, r5 = 0.f, r6 = 0.f, r7 = 0.f;
    int i = 0;
    for (; i + 8 <= sg; i += 8) {
        r0 += supersum[(size_t)(i + 0) * FEAT + f];
        r1 += supersum[(size_t)(i + 1) * FEAT + f];
        r2 += supersum[(size_t)(i + 2) * FEAT + f];
        r3 += supersum[(size_t)(i + 3) * FEAT + f];
        r4 += supersum[(size_t)(i + 4) * FEAT + f];
        r5 += supersum[(size_t)(i + 5) * FEAT + f];
        r6 += supersum[(size_t)(i + 6) * FEAT + f];
        r7 += supersum[(size_t)(i + 7) * FEAT + f];
    }
    for (; i < sg; ++i) r0 += supersum[(size_t)i * FEAT + f];
    i = sg * SUPER;
    for (; i + 8 <= c; i += 8) {
        r0 += colsum[(size_t)(i + 0) * FEAT + f];
        r1 += colsum[(size_t)(i + 1) * FEAT + f];
        r2 += colsum[(size_t)(i + 2) * FEAT + f];
        r3 += colsum[(size_t)(i + 3) * FEAT + f];
        r4 += colsum[(size_t)(i + 4) * FEAT + f];
        r5 += colsum[(size_t)(i + 5) * FEAT + f];
        r6 += colsum[(size_t)(i + 6) * FEAT + f];
        r7 += colsum[(size_t)(i + 7) * FEAT + f];
    }
    for (; i < c; ++i) r0 += colsum[(size_t)i * FEAT + f];
    float run = ((r0 + r1) + (r2 + r3)) + ((r4 + r5) + (r6 + r7));

    float d0 = 0.f, d1 = 0.f, d2 = 0.f, d3 = 0.f;
    float d4 = 0.f, d5 = 0.f, d6 = 0.f, d7 = 0.f;
    int j = 0;
    for (; j + 4 <= cnt; j += 4) {
        const int e0 = evb[j + 0], e1 = evb[j + 1];
        const int e2 = evb[j + 2], e3 = evb[j + 3];
        const float v0 = emb[(size_t)(e0 >> 4) * FEAT + f];
        const float v1 = emb[(size_t)(e1 >> 4) * FEAT + f];
        const float v2 = emb[(size_t)(e2 >> 4) * FEAT + f];
        const float v3 = emb[(size_t)(e3 >> 4) * FEAT + f];
        APPLY_EVENT(e0, v0);
        APPLY_EVENT(e1, v1);
        APPLY_EVENT(e2, v2);
        APPLY_EVENT(e3, v3);
    }
    for (; j < cnt; ++j) {
        const int e0 = evb[j];
        const float v0 = emb[(size_t)(e0 >> 4) * FEAT + f];
        APPLY_EVENT(e0, v0);
    }

    float* o = out + (size_t)c * CHUNK * FEAT + f;
    run += d0; o[0 * FEAT] = run;
    run += d1; o[1 * FEAT] = run;
    run += d2; o[2 * FEAT] = run;
    run += d3; o[3 * FEAT] = run;
    run += d4; o[4 * FEAT] = run;
    run += d5; o[5 * FEAT] = run;
    run += d6; o[6 * FEAT] = run;
    run += d7; o[7 * FEAT] = run;
}

extern "C" void kernel_launch(void* const* d_in, const int* in_sizes, int n_in,
                              void* d_out, int out_size, void* d_ws, size_t ws_size,
                              hipStream_t stream) {
    const float* emb     = (const float*)d_in[0];
    const int* starts    = (const int*)d_in[1];
    const int* ends      = (const int*)d_in[2];
    const int* num_nodes = (const int*)d_in[3];
    float* out           = (float*)d_out;

    float* colsum   = (float*)d_ws;                              // 1 MB
    float* supersum = colsum + (size_t)NCHUNKS * FEAT;           // 32 KB
    int* evcnt      = (int*)(supersum + (size_t)NSUPER * FEAT);  // 4 KB
    int* evbuf      = evcnt + NCHUNKS;                           // 16 MB

    // supersum accumulated via atomics -> must start at zero
    hipMemsetAsync(supersum, 0, (size_t)NSUPER * FEAT * sizeof(float), stream);

    classify_colsum_kernel<<<NCHUNKS, FEAT, 0, stream>>>(
        emb, starts, ends, num_nodes, colsum, supersum, evcnt, evbuf);
    scan_kernel<<<NCHUNKS, FEAT, 0, stream>>>(
        emb, colsum, supersum, evcnt, evbuf, out);
}